// Round 7
// baseline (172.875 us; speedup 1.0000x reference)
//
#include <hip/hip_runtime.h>
#include <math.h>

#define L_SEQ 512
#define BSZ 2
#define NH 8
#define HD 32
#define E 256
#define SCALE 0.17677669529663687f
#define SROW 520   // s_lds row stride: (h*520+m)%32 = (h*8+m)%32 -> conflict-free patterns

typedef float f32x4 __attribute__((ext_vector_type(4)));

// Workspace:
//   q2     : (B, L, E)       1KB row per (b,l)
//   kh, vh : (B*NH, L, HD)   head-major
//   oh2    : (B, L, E)
//   scores : (B*NH, L, L)    qk*SCALE + mask

// ---------------- Kernel 1: in-projection ----------------
// grid (256 rowgrps, 12 colgrps) -> 3072 blocks (12/CU). Block: 4 rows x 64 cols.
__global__ void inproj_kernel(const float* __restrict__ query,
                              const float* __restrict__ W,
                              const float* __restrict__ bias,
                              float* __restrict__ q2,
                              float* __restrict__ kh,
                              float* __restrict__ vh) {
    int rg = blockIdx.x;             // rows rg*4 .. rg*4+3 (row = l*B + b)
    int cg3 = blockIdx.y;            // out-features cg3*64 .. +63 (of 768)
    int t = threadIdx.x;             // 0..255
    __shared__ float xs[4][E];
#pragma unroll
    for (int r = 0; r < 4; ++r) xs[r][t] = query[(size_t)(rg * 4 + r) * E + t];
    __syncthreads();

    int c = t & 7, cg = t >> 3;
#pragma unroll
    for (int pp = 0; pp < 2; ++pp) {
        int col768 = cg3 * 64 + pp * 32 + cg;
        const float4* wp = (const float4*)(W + (size_t)col768 * E);
        float a0 = 0.f, a1 = 0.f, a2 = 0.f, a3 = 0.f;
#pragma unroll
        for (int kk = 0; kk < 8; ++kk) {
            float4 w  = wp[c + kk * 8];
            float4 x0 = ((const float4*)xs[0])[c + kk * 8];
            float4 x1 = ((const float4*)xs[1])[c + kk * 8];
            float4 x2 = ((const float4*)xs[2])[c + kk * 8];
            float4 x3 = ((const float4*)xs[3])[c + kk * 8];
            a0 += w.x * x0.x + w.y * x0.y + w.z * x0.z + w.w * x0.w;
            a1 += w.x * x1.x + w.y * x1.y + w.z * x1.z + w.w * x1.w;
            a2 += w.x * x2.x + w.y * x2.y + w.z * x2.z + w.w * x2.w;
            a3 += w.x * x3.x + w.y * x3.y + w.z * x3.z + w.w * x3.w;
        }
#pragma unroll
        for (int off = 1; off <= 4; off <<= 1) {
            a0 += __shfl_xor(a0, off);
            a1 += __shfl_xor(a1, off);
            a2 += __shfl_xor(a2, off);
            a3 += __shfl_xor(a3, off);
        }
        if (c == 0) {
            int p = col768 >> 8, col = col768 & 255;
            float bb = bias[col768];
            float res[4] = {a0, a1, a2, a3};
#pragma unroll
            for (int r = 0; r < 4; ++r) {
                int row = rg * 4 + r, l = row >> 1, b = row & 1;
                float val = res[r] + bb;
                if (p == 0) {
                    q2[((size_t)b * L_SEQ + l) * E + col] = val;
                } else {
                    int h = col >> 5, d = col & 31;
                    float* dst = (p == 1) ? kh : vh;
                    dst[((size_t)(b * NH + h) * L_SEQ + l) * HD + d] = val;
                }
            }
        }
    }
}

// ---------------- Kernel 2: QK^T * scale + mask -> scores ----------------
// grid (16 heads, 64 l-grps) -> 1024 blocks (4/CU). k rows in registers.
__global__ void qk_kernel(const float* __restrict__ q2,
                          const float* __restrict__ kh,
                          const float* __restrict__ mask,
                          float* __restrict__ scores) {
    int n = blockIdx.x;              // 0..15
    int b = n >> 3, h = n & 7;
    int l0 = blockIdx.y * 8;
    int t = threadIdx.x, lane = t & 63, w = t >> 6;

    __shared__ float qs[8][32];
    if (t < 64) {
        int row = t >> 3, quad = t & 7;
        float4 qv = *(const float4*)(q2 + ((size_t)b * L_SEQ + l0 + row) * E + h * HD + quad * 4);
        ((float4*)qs[row])[quad] = qv;
    }
    __syncthreads();

    f32x4 ka[8], kb[8];
    const float* kbase = kh + (size_t)n * L_SEQ * HD;
    {
        const f32x4* pa = (const f32x4*)(kbase + (size_t)(w * 128 + lane) * HD);
        const f32x4* pb = (const f32x4*)(kbase + (size_t)(w * 128 + 64 + lane) * HD);
#pragma unroll
        for (int i = 0; i < 8; ++i) { ka[i] = pa[i]; kb[i] = pb[i]; }
    }

#pragma unroll
    for (int li = 0; li < 8; ++li) {
        int l = l0 + li;
        float da = 0.f, db = 0.f;
#pragma unroll
        for (int i = 0; i < 8; ++i) {
            float4 qv = ((const float4*)qs[li])[i];
            da += ka[i].x * qv.x + ka[i].y * qv.y + ka[i].z * qv.z + ka[i].w * qv.w;
            db += kb[i].x * qv.x + kb[i].y * qv.y + kb[i].z * qv.z + kb[i].w * qv.w;
        }
        size_t off = ((size_t)n * L_SEQ + l) * L_SEQ;
        const float* mrow = mask + (size_t)l * L_SEQ;
        scores[off + w * 128 + lane]      = da * SCALE + mrow[w * 128 + lane];
        scores[off + w * 128 + 64 + lane] = db * SCALE + mrow[w * 128 + 64 + lane];
    }
}

// ---------------- Kernel 3: rel-bias stream + softmax -> attn ----------------
// One block per (b,l), 512 thr = 8 waves. Phase 1: explicit double-buffered
// register batches of 8 -> 8-16 loads in flight per wave (latency hiding).
// __launch_bounds__(512,4): VGPR <=128 -> 16 waves/CU.
__global__ __launch_bounds__(512, 4)
void relattn_kernel(const float* __restrict__ q2,
                    const float* __restrict__ rpe,
                    const float* __restrict__ scores,
                    float* __restrict__ attn_out) {
    int bid = blockIdx.x;            // b*512 + l
    int b = bid >> 9, l = bid & (L_SEQ - 1);
    int t = threadIdx.x;
    int lane = t & 63, wid = t >> 6;

    __shared__ float qs[E];
    __shared__ float s_lds[NH * SROW];

    if (t < E) qs[t] = q2[((size_t)b * L_SEQ + l) * E + t];
    __syncthreads();

    // Phase 1: wave w streams rows m = w*64 .. w*64+63 (64KB contiguous).
    f32x4 qc = ((const f32x4*)qs)[lane];   // head lane>>3, quad lane&7
    int h1 = lane >> 3;
    const float* rbase = rpe + ((size_t)(b * L_SEQ + l)) * L_SEQ * E;
    // lane's element for row m: (m*64 + lane) in f32x4 units
    const f32x4* rp = (const f32x4*)rbase + (size_t)(wid * 64) * 64 + lane;

    f32x4 buf[2][8];
#pragma unroll
    for (int j = 0; j < 8; ++j) buf[0][j] = rp[j * 64];

#pragma unroll
    for (int blk = 0; blk < 8; ++blk) {
        const int cur = blk & 1, nxt = cur ^ 1;
        if (blk < 7) {
#pragma unroll
            for (int j = 0; j < 8; ++j) buf[nxt][j] = rp[(blk + 1) * 8 * 64 + j * 64];
        }
#pragma unroll
        for (int j = 0; j < 8; ++j) {
            f32x4 rv = buf[cur][j];
            float part = rv.x * qc.x + rv.y * qc.y + rv.z * qc.z + rv.w * qc.w;
            part += __shfl_xor(part, 1);
            part += __shfl_xor(part, 2);
            part += __shfl_xor(part, 4);
            if ((lane & 7) == 0) s_lds[h1 * SROW + wid * 64 + blk * 8 + j] = part;
        }
    }
    __syncthreads();

    // Phase 2: softmax; wave w owns head w.
    int h = wid;
    const float* srow = scores + ((size_t)(b * NH + h) * L_SEQ + l) * L_SEQ;
    float sv[8];
    float mx = -1e30f;
#pragma unroll
    for (int i = 0; i < 8; ++i) {
        int m = i * 64 + lane;
        sv[i] = s_lds[h * SROW + m] + srow[m];
        mx = fmaxf(mx, sv[i]);
    }
#pragma unroll
    for (int off = 32; off > 0; off >>= 1) mx = fmaxf(mx, __shfl_xor(mx, off));
    float sum = 0.f;
#pragma unroll
    for (int i = 0; i < 8; ++i) { sv[i] = __expf(sv[i] - mx); sum += sv[i]; }
#pragma unroll
    for (int off = 32; off > 0; off >>= 1) sum += __shfl_xor(sum, off);
    float inv = 1.0f / sum;

    float* arow = attn_out + ((size_t)(b * NH + h) * L_SEQ + l) * L_SEQ;
#pragma unroll
    for (int i = 0; i < 8; ++i) {
        arow[i * 64 + lane] = sv[i] * inv;
    }
}

// ---------------- Kernel 4: PV (attn @ v) ----------------
// grid (16 heads, 32 l-grps) -> 512 blocks (2/CU). v staged in LDS (XOR-swizzled
// quads: conflict-free b128 reads), reused across 16 l's.
__global__ void pv_kernel(const float* __restrict__ attn,
                          const float* __restrict__ vh,
                          float* __restrict__ oh2) {
    int n = blockIdx.x;              // 0..15
    int b = n >> 3, h = n & 7;
    int lg = blockIdx.y;             // l's lg*16 .. +15
    int t = threadIdx.x;             // 0..255

    __shared__ float vlds[L_SEQ * HD];   // swizzled: row m, quad slot (dq ^ (m&7))
    __shared__ float pl[L_SEQ];
    __shared__ float red[32][33];

    const f32x4* vsrc = (const f32x4*)(vh + (size_t)n * L_SEQ * HD);
#pragma unroll
    for (int j = 0; j < 16; ++j) {
        int qg = j * 256 + t;            // global quad index 0..4095
        int m = qg >> 3, dq = qg & 7;
        f32x4 v4 = vsrc[qg];
        int qsw = dq ^ (m & 7);
        *(f32x4*)&vlds[m * HD + qsw * 4] = v4;
    }
    __syncthreads();

    int mg = t >> 3, dq = t & 7;         // mg 0..31; per-thread m = i*32+mg
    int qsw = dq ^ (mg & 7);             // (i*32+mg)&7 == mg&7
    for (int li = 0; li < 16; ++li) {
        int l = lg * 16 + li;
        const float2* prow = (const float2*)(attn + ((size_t)n * L_SEQ + l) * L_SEQ);
        *(float2*)&pl[t * 2] = prow[t];
        __syncthreads();

        float ax = 0.f, ay = 0.f, az = 0.f, aw = 0.f;
#pragma unroll
        for (int i = 0; i < 16; ++i) {
            int m = i * 32 + mg;
            f32x4 v4 = *(const f32x4*)&vlds[m * HD + qsw * 4];
            float p = pl[m];
            ax += p * v4.x; ay += p * v4.y; az += p * v4.z; aw += p * v4.w;
        }
        red[mg][dq * 4 + 0] = ax;
        red[mg][dq * 4 + 1] = ay;
        red[mg][dq * 4 + 2] = az;
        red[mg][dq * 4 + 3] = aw;
        __syncthreads();

        if (t < 32) {
            float s = 0.f;
#pragma unroll
            for (int g = 0; g < 32; ++g) s += red[g][t];
            oh2[((size_t)b * L_SEQ + l) * E + h * HD + t] = s;
        }
        __syncthreads();
    }
}

// ---------------- Kernel 5: out-projection ----------------
// grid (256 rowgrps, 4 colgrps) -> 1024 blocks. Block: 4 rows x 64 cols.
__global__ void outproj_kernel(const float* __restrict__ oh2,
                               const float* __restrict__ W,
                               const float* __restrict__ bias,
                               float* __restrict__ out) {
    int rg = blockIdx.x;
    int cg3 = blockIdx.y;            // cols cg3*64 .. +63
    int t = threadIdx.x;
    __shared__ float xs[4][E];
#pragma unroll
    for (int r = 0; r < 4; ++r) {
        int row = rg * 4 + r, l = row >> 1, b = row & 1;
        xs[r][t] = oh2[((size_t)b * L_SEQ + l) * E + t];
    }
    __syncthreads();

    int c = t & 7, cg = t >> 3;
#pragma unroll
    for (int pp = 0; pp < 2; ++pp) {
        int col = cg3 * 64 + pp * 32 + cg;
        const float4* wp = (const float4*)(W + (size_t)col * E);
        float a0 = 0.f, a1 = 0.f, a2 = 0.f, a3 = 0.f;
#pragma unroll
        for (int kk = 0; kk < 8; ++kk) {
            float4 w  = wp[c + kk * 8];
            float4 x0 = ((const float4*)xs[0])[c + kk * 8];
            float4 x1 = ((const float4*)xs[1])[c + kk * 8];
            float4 x2 = ((const float4*)xs[2])[c + kk * 8];
            float4 x3 = ((const float4*)xs[3])[c + kk * 8];
            a0 += w.x * x0.x + w.y * x0.y + w.z * x0.z + w.w * x0.w;
            a1 += w.x * x1.x + w.y * x1.y + w.z * x1.z + w.w * x1.w;
            a2 += w.x * x2.x + w.y * x2.y + w.z * x2.z + w.w * x2.w;
            a3 += w.x * x3.x + w.y * x3.y + w.z * x3.z + w.w * x3.w;
        }
#pragma unroll
        for (int off = 1; off <= 4; off <<= 1) {
            a0 += __shfl_xor(a0, off);
            a1 += __shfl_xor(a1, off);
            a2 += __shfl_xor(a2, off);
            a3 += __shfl_xor(a3, off);
        }
        if (c == 0) {
            float bb = bias[col];
            float res[4] = {a0, a1, a2, a3};
#pragma unroll
            for (int r = 0; r < 4; ++r) {
                out[(size_t)(rg * 4 + r) * E + col] = res[r] + bb;
            }
        }
    }
}

extern "C" void kernel_launch(void* const* d_in, const int* in_sizes, int n_in,
                              void* d_out, int out_size, void* d_ws, size_t ws_size,
                              hipStream_t stream) {
    const float* query = (const float*)d_in[0];
    // d_in[1] = key, d_in[2] = value -- UNUSED (reference projects only query)
    const float* rpe   = (const float*)d_in[3];
    const float* mask  = (const float*)d_in[4];
    const float* Win   = (const float*)d_in[5];
    const float* bin   = (const float*)d_in[6];
    const float* Wout  = (const float*)d_in[7];
    const float* bout  = (const float*)d_in[8];

    float* out  = (float*)d_out;                            // (L,B,E)
    float* attn = (float*)d_out + (size_t)L_SEQ * BSZ * E;  // (B*H,L,L)

    float* q2     = (float*)d_ws;                           // (B,L,E)
    float* kh     = q2  + (size_t)BSZ * L_SEQ * E;          // (B*H,L,D)
    float* vh     = kh  + (size_t)BSZ * NH * L_SEQ * HD;    // (B*H,L,D)
    float* oh2    = vh  + (size_t)BSZ * NH * L_SEQ * HD;    // (B,L,E)
    float* scores = oh2 + (size_t)BSZ * L_SEQ * E;          // (B*H,L,L)

    inproj_kernel<<<dim3(256, 12), 256, 0, stream>>>(query, Win, bin, q2, kh, vh);
    qk_kernel<<<dim3(BSZ * NH, 64), 256, 0, stream>>>(q2, kh, mask, scores);
    relattn_kernel<<<BSZ * L_SEQ, 512, 0, stream>>>(q2, rpe, scores, attn);
    pv_kernel<<<dim3(BSZ * NH, 32), 256, 0, stream>>>(attn, vh, oh2);
    outproj_kernel<<<dim3(256, 4), 256, 0, stream>>>(oh2, Wout, bout, out);
}